// Round 1
// baseline (277.712 us; speedup 1.0000x reference)
//
#include <hip/hip_runtime.h>

// SharedAdditiveKAN: y = spline(x) @ mix^T + bias
// x: [65536, 512] fp32; bases/slopes: [512, 16] fp32; mix: [512, 512] fp32; bias: [512] fp32
// y: [65536, 512] fp32.
//
// Strategy: spline -> bf16, GEMM via mfma_f32_16x16x32_bf16.
// Block tile: BM=128 x BN=512 (full N => x read exactly once, spline computed once).
// 512 threads = 8 waves (2 m x 4 n), each wave 64x128 = 4x8 16x16 frags (128 acc VGPRs).
// A staged via VALU spline + ds_write (XOR-swizzled LDS); B staged via global_load_lds
// width=16 from pre-converted bf16 mix in ws (LLC-hot).

#define DIMK 512
#define DIMN 512
#define GRID_G 16

typedef unsigned short u16;
typedef unsigned int u32;
typedef __attribute__((ext_vector_type(8))) __bf16 bf16x8;
typedef __attribute__((ext_vector_type(4))) float f32x4;

__device__ __forceinline__ u32 bf16rne(float f) {
    u32 u = __float_as_uint(f);
    return (u + 0x7fffu + ((u >> 16) & 1u)) >> 16;  // round-to-nearest-even
}

// Prep: convert mix fp32 -> bf16 (ushort bits) into ws; build interleaved
// (base, slope) float2 table so the main kernel gathers one 8B load per element.
__global__ void prep_kernel(const float* __restrict__ mix,
                            const float* __restrict__ bases,
                            const float* __restrict__ slopes,
                            u16* __restrict__ mixb,
                            float2* __restrict__ tab) {
    int t = blockIdx.x * 256 + threadIdx.x;            // 65536 threads
    float4 v = reinterpret_cast<const float4*>(mix)[t]; // 4 mix elems each
    ushort4 o;
    o.x = (u16)bf16rne(v.x);
    o.y = (u16)bf16rne(v.y);
    o.z = (u16)bf16rne(v.z);
    o.w = (u16)bf16rne(v.w);
    reinterpret_cast<ushort4*>(mixb)[t] = o;
    if (t < DIMK * GRID_G) {
        tab[t] = make_float2(bases[t], slopes[t]);
    }
}

__global__ __launch_bounds__(512, 2) void kan_kernel(
    const float* __restrict__ x, const float2* __restrict__ tab,
    const u16* __restrict__ mixb, const float* __restrict__ bias,
    float* __restrict__ y) {
    // LDS: XOR-swizzled chunk layout. Row r, global k-chunk c (16B = 8 bf16)
    // lives at chunk index (r<<2) | (c ^ ((r>>1)&3)). This makes both the
    // contiguous lane*16 global_load_lds writes and the b128 frag reads
    // (16 consecutive rows, fixed chunk) 2-way-or-better on banks.
    __shared__ __align__(16) u16 sA[128 * 32];  // 8 KB
    __shared__ __align__(16) u16 sB[512 * 32];  // 32 KB

    const int tid = threadIdx.x;
    const int lane = tid & 63;
    const int wid = tid >> 6;       // 0..7
    const int quad = lane >> 4;     // 0..3
    const int l15 = lane & 15;
    const int wave_m = wid >> 2;    // 0..1
    const int wave_n = wid & 3;     // 0..3
    const int m0 = blockIdx.x * 128;

    // A staging: thread t handles row ar (0..127), k-chunk akg (0..3) = 8 elems
    const int ar = tid >> 2;
    const int akg = tid & 3;
    const int awchunk = (ar << 2) | (akg ^ ((ar >> 1) & 3));
    const float4* xrow =
        reinterpret_cast<const float4*>(x + (size_t)(m0 + ar) * DIMK) + akg * 2;

    f32x4 acc[4][8];
#pragma unroll
    for (int i = 0; i < 4; i++)
#pragma unroll
        for (int j = 0; j < 8; j++) acc[i][j] = (f32x4){0.f, 0.f, 0.f, 0.f};

    // preload x for kt=0
    float4 xa = xrow[0];
    float4 xb = xrow[1];

    for (int kt = 0; kt < 16; ++kt) {
        // ---- stage A: 8 splines per thread ----
        float xs[8] = {xa.x, xa.y, xa.z, xa.w, xb.x, xb.y, xb.z, xb.w};
        const int dbase = kt * 32 + akg * 8;
        float2 bs[8];
        float tv[8];
        int idxv[8];
#pragma unroll
        for (int j = 0; j < 8; j++) {
            // EXACT replication of reference index math (fp32):
            // x_norm = clip((x+1)*0.5, 0, 0.999999); t = x_norm*16; idx = trunc(t)
            float xn = fminf(fmaxf((xs[j] + 1.0f) * 0.5f, 0.0f), 0.999999f);
            float tt = xn * 16.0f;
            int idx = (int)tt;
            if (idx > 15) idx = 15;
            tv[j] = tt;
            idxv[j] = idx;
            bs[j] = tab[((dbase + j) << 4) + idx];  // 8B L2 gather
        }
        u32 h[8];
#pragma unroll
        for (int j = 0; j < 8; j++) {
            float sp = bs[j].x + bs[j].y * (tv[j] - (float)idxv[j]);
            h[j] = bf16rne(sp);
        }
        int4 pk = make_int4((int)(h[0] | (h[1] << 16)), (int)(h[2] | (h[3] << 16)),
                            (int)(h[4] | (h[5] << 16)), (int)(h[6] | (h[7] << 16)));
        *reinterpret_cast<int4*>(&sA[awchunk * 8]) = pk;

        // ---- stage B: global_load_lds width 16, swizzle-matched lane mapping ----
#pragma unroll
        for (int i = 0; i < 4; i++) {
            int grp = wid * 4 + i;              // 16-row group, 0..31
            int n = grp * 16 + (lane >> 2);
            int c = (lane & 3) ^ ((n >> 1) & 3);  // global k-chunk this lane fetches
            const u16* gsrc = mixb + (size_t)n * DIMK + kt * 32 + c * 8;
            __builtin_amdgcn_global_load_lds(
                (const __attribute__((address_space(1))) void*)gsrc,
                (__attribute__((address_space(3))) void*)(&sB[grp * 512]),
                16, 0, 0);
        }
        __syncthreads();  // drains glds (vmcnt) + ds_writes (lgkmcnt)

        // prefetch next x tile during compute phase
        if (kt < 15) {
            xa = xrow[(kt + 1) * 8];
            xb = xrow[(kt + 1) * 8 + 1];
        }

        // ---- compute: 32 MFMAs per wave ----
        bf16x8 afrag[4];
#pragma unroll
        for (int fm = 0; fm < 4; fm++) {
            int m_l = wave_m * 64 + fm * 16 + l15;
            int ci = (m_l << 2) | (quad ^ ((m_l >> 1) & 3));
            afrag[fm] = *reinterpret_cast<const bf16x8*>(&sA[ci * 8]);
        }
#pragma unroll
        for (int fn = 0; fn < 8; fn++) {
            int n_l = wave_n * 128 + fn * 16 + l15;
            int ci = (n_l << 2) | (quad ^ ((n_l >> 1) & 3));
            bf16x8 bfrag = *reinterpret_cast<const bf16x8*>(&sB[ci * 8]);
#pragma unroll
            for (int fm = 0; fm < 4; fm++)
                acc[fm][fn] = __builtin_amdgcn_mfma_f32_16x16x32_bf16(
                    afrag[fm], bfrag, acc[fm][fn], 0, 0, 0);
        }
        __syncthreads();  // sA/sB free for next kt
    }

    // ---- epilogue: C/D layout col=lane&15, row=quad*4+j ----
#pragma unroll
    for (int fn = 0; fn < 8; fn++) {
        int o = wave_n * 128 + fn * 16 + l15;
        float bv = bias[o];
#pragma unroll
        for (int fm = 0; fm < 4; fm++) {
            int row = m0 + wave_m * 64 + fm * 16 + quad * 4;
            float* yp = y + (size_t)row * DIMN + o;
#pragma unroll
            for (int j = 0; j < 4; j++)
                yp[(size_t)j * DIMN] = acc[fm][fn][j] + bv;
        }
    }
}

extern "C" void kernel_launch(void* const* d_in, const int* in_sizes, int n_in,
                              void* d_out, int out_size, void* d_ws, size_t ws_size,
                              hipStream_t stream) {
    const float* x = (const float*)d_in[0];
    const float* bases = (const float*)d_in[1];
    const float* slopes = (const float*)d_in[2];
    const float* mix = (const float*)d_in[3];
    const float* bias = (const float*)d_in[4];
    float* y = (float*)d_out;

    u16* mixb = (u16*)d_ws;                                   // 512 KB bf16 mix
    float2* tab = (float2*)((char*)d_ws + 512 * 1024);        // 64 KB (base,slope)

    hipLaunchKernelGGL(prep_kernel, dim3(256), dim3(256), 0, stream,
                       mix, bases, slopes, mixb, tab);
    hipLaunchKernelGGL(kan_kernel, dim3(512), dim3(512), 0, stream,
                       x, tab, mixb, bias, y);
}

// Round 2
// 263.531 us; speedup vs baseline: 1.0538x; 1.0538x over previous
//
#include <hip/hip_runtime.h>

// SharedAdditiveKAN: y = spline(x) @ mix^T + bias
// x: [65536, 512] fp32; bases/slopes: [512, 16] fp32; mix: [512, 512] fp32; bias: [512] fp32
// y: [65536, 512] fp32.
//
// R2 change: spline (base,slope) table moved to LDS (bf16-pair packed in u32,
// stride-17 padded), loaded once per block. R1's per-element global/L2 gathers
// (8192 scattered 8B reqs per CU per kt) were the latency bottleneck
// (MfmaUtil 12%, VALUBusy 18%, HBM 24% -- all idle).
//
// GEMM: BM=128 x BN=512 (full N => x read exactly once, spline computed once),
// BK=32, 512 threads = 8 waves (2m x 4n), mfma_f32_16x16x32_bf16, 4x8 frags/wave.
// A staged via VALU spline + ds_write (XOR-swizzled); B via global_load_lds
// width=16 from pre-converted bf16 mix in ws (LLC-hot).

#define DIMK 512
#define DIMN 512
#define GRID_G 16

typedef unsigned short u16;
typedef unsigned int u32;
typedef __attribute__((ext_vector_type(8))) __bf16 bf16x8;
typedef __attribute__((ext_vector_type(4))) float f32x4;

__device__ __forceinline__ u32 bf16rne(float f) {
    u32 u = __float_as_uint(f);
    return (u + 0x7fffu + ((u >> 16) & 1u)) >> 16;  // round-to-nearest-even
}

// Prep: convert mix fp32 -> bf16 (ushort bits) into ws.
__global__ void prep_kernel(const float* __restrict__ mix,
                            u16* __restrict__ mixb) {
    int t = blockIdx.x * 256 + threadIdx.x;             // 65536 threads
    float4 v = reinterpret_cast<const float4*>(mix)[t]; // 4 mix elems each
    ushort4 o;
    o.x = (u16)bf16rne(v.x);
    o.y = (u16)bf16rne(v.y);
    o.z = (u16)bf16rne(v.z);
    o.w = (u16)bf16rne(v.w);
    reinterpret_cast<ushort4*>(mixb)[t] = o;
}

__global__ __launch_bounds__(512, 2) void kan_kernel(
    const float* __restrict__ x, const float* __restrict__ bases,
    const float* __restrict__ slopes, const u16* __restrict__ mixb,
    const float* __restrict__ bias, float* __restrict__ y) {
    // Spline table in LDS: (base,slope) as packed bf16 pair, stride 17 words
    // per dim so the 16-value idx gather spreads over banks (~2-way, ~free).
    __shared__ u32 s_tab[DIMK * 17];            // 34816 B
    // XOR-swizzled tiles: row r, k-chunk c (16B) at chunk (r<<2)|(c^((r>>1)&3)).
    __shared__ __align__(16) u16 sA[128 * 32];  // 8 KB
    __shared__ __align__(16) u16 sB[512 * 32];  // 32 KB
    // total 75.7 KB -> 2 blocks/CU

    const int tid = threadIdx.x;
    const int lane = tid & 63;
    const int wid = tid >> 6;       // 0..7
    const int quad = lane >> 4;     // 0..3
    const int l15 = lane & 15;
    const int wave_m = wid >> 2;    // 0..1
    const int wave_n = wid & 3;     // 0..3
    const int m0 = blockIdx.x * 128;

    // ---- one-time: load spline table into LDS (coalesced fp32 reads) ----
#pragma unroll
    for (int k = 0; k < 16; k++) {
        int i = tid + k * 512;      // 0..8191 over [D=512][G=16]
        u32 p = bf16rne(bases[i]) | (bf16rne(slopes[i]) << 16);
        s_tab[(i >> 4) * 17 + (i & 15)] = p;
    }

    // A staging: thread t handles row ar (0..127), k-chunk akg (0..3) = 8 elems
    const int ar = tid >> 2;
    const int akg = tid & 3;
    const int awchunk = (ar << 2) | (akg ^ ((ar >> 1) & 3));
    const float4* xrow =
        reinterpret_cast<const float4*>(x + (size_t)(m0 + ar) * DIMK) + akg * 2;

    f32x4 acc[4][8];
#pragma unroll
    for (int i = 0; i < 4; i++)
#pragma unroll
        for (int j = 0; j < 8; j++) acc[i][j] = (f32x4){0.f, 0.f, 0.f, 0.f};

    // preload x for kt=0
    float4 xa = xrow[0];
    float4 xb = xrow[1];

    __syncthreads();  // s_tab ready

    for (int kt = 0; kt < 16; ++kt) {
        // ---- stage A: 8 splines per thread, table gathered from LDS ----
        float xs[8] = {xa.x, xa.y, xa.z, xa.w, xb.x, xb.y, xb.z, xb.w};
        const int dbase = kt * 32 + akg * 8;
        u32 h[8];
#pragma unroll
        for (int j = 0; j < 8; j++) {
            // EXACT replication of reference index math (fp32):
            // x_norm = clip((x+1)*0.5, 0, 0.999999); t = x_norm*16; idx=trunc(t)
            // (x+1) then *0.5: *0.5 is exact, so rounding matches (x-min)/range.
            float xn = fminf(fmaxf((xs[j] + 1.0f) * 0.5f, 0.0f), 0.999999f);
            float tt = xn * 16.0f;
            int idx = (int)tt;  // 0..15 guaranteed (tt <= 15.999984)
            u32 p = s_tab[(dbase + j) * 17 + idx];
            float base = __uint_as_float(p << 16);
            float slope = __uint_as_float(p & 0xffff0000u);
            float sp = fmaf(slope, tt - (float)idx, base);
            h[j] = bf16rne(sp);
        }
        int4 pk = make_int4((int)(h[0] | (h[1] << 16)), (int)(h[2] | (h[3] << 16)),
                            (int)(h[4] | (h[5] << 16)), (int)(h[6] | (h[7] << 16)));
        *reinterpret_cast<int4*>(&sA[awchunk * 8]) = pk;

        // ---- stage B: global_load_lds width 16, swizzle-matched lane mapping ----
#pragma unroll
        for (int i = 0; i < 4; i++) {
            int grp = wid * 4 + i;                // 16-row group, 0..31
            int n = grp * 16 + (lane >> 2);
            int c = (lane & 3) ^ ((n >> 1) & 3);  // global k-chunk this lane fetches
            const u16* gsrc = mixb + (size_t)n * DIMK + kt * 32 + c * 8;
            __builtin_amdgcn_global_load_lds(
                (const __attribute__((address_space(1))) void*)gsrc,
                (__attribute__((address_space(3))) void*)(&sB[grp * 512]),
                16, 0, 0);
        }
        __syncthreads();  // drains glds (vmcnt) + ds_writes (lgkmcnt)

        // prefetch next x tile during compute phase
        if (kt < 15) {
            xa = xrow[(kt + 1) * 8];
            xb = xrow[(kt + 1) * 8 + 1];
        }

        // ---- compute: 32 MFMAs per wave ----
        bf16x8 afrag[4];
#pragma unroll
        for (int fm = 0; fm < 4; fm++) {
            int m_l = wave_m * 64 + fm * 16 + l15;
            int ci = (m_l << 2) | (quad ^ ((m_l >> 1) & 3));
            afrag[fm] = *reinterpret_cast<const bf16x8*>(&sA[ci * 8]);
        }
#pragma unroll
        for (int fn = 0; fn < 8; fn++) {
            int n_l = wave_n * 128 + fn * 16 + l15;
            int ci = (n_l << 2) | (quad ^ ((n_l >> 1) & 3));
            bf16x8 bfrag = *reinterpret_cast<const bf16x8*>(&sB[ci * 8]);
#pragma unroll
            for (int fm = 0; fm < 4; fm++)
                acc[fm][fn] = __builtin_amdgcn_mfma_f32_16x16x32_bf16(
                    afrag[fm], bfrag, acc[fm][fn], 0, 0, 0);
        }
        __syncthreads();  // sA/sB free for next kt
    }

    // ---- epilogue: C/D layout col=lane&15, row=quad*4+j ----
#pragma unroll
    for (int fn = 0; fn < 8; fn++) {
        int o = wave_n * 128 + fn * 16 + l15;
        float bv = bias[o];
#pragma unroll
        for (int fm = 0; fm < 4; fm++) {
            int row = m0 + wave_m * 64 + fm * 16 + quad * 4;
            float* yp = y + (size_t)row * DIMN + o;
#pragma unroll
            for (int j = 0; j < 4; j++)
                yp[(size_t)j * DIMN] = acc[fm][fn][j] + bv;
        }
    }
}

extern "C" void kernel_launch(void* const* d_in, const int* in_sizes, int n_in,
                              void* d_out, int out_size, void* d_ws, size_t ws_size,
                              hipStream_t stream) {
    const float* x = (const float*)d_in[0];
    const float* bases = (const float*)d_in[1];
    const float* slopes = (const float*)d_in[2];
    const float* mix = (const float*)d_in[3];
    const float* bias = (const float*)d_in[4];
    float* y = (float*)d_out;

    u16* mixb = (u16*)d_ws;  // 512 KB bf16 mix

    hipLaunchKernelGGL(prep_kernel, dim3(256), dim3(256), 0, stream, mix, mixb);
    hipLaunchKernelGGL(kan_kernel, dim3(512), dim3(512), 0, stream,
                       x, bases, slopes, mixb, bias, y);
}